// Round 9
// baseline (138.944 us; speedup 1.0000x reference)
//
#include <hip/hip_runtime.h>
#include <hip/hip_fp16.h>

// MinGRU single-pass fused pipeline, round 16 = r15's deep-pipelined K loop
// with the x->bf16 prologue DELETED. r15 showed {dbuf DMA pipeline, 4/CU}
// buys ~8us on the gemm but the 9us prologue ate it (total flat vs r10).
// Fix: stage X as RAW FP32 via global_load_lds at BK=32:
//   X [128][32] fp32 = 16KB + W {Wz,Wh}[64][32] bf16 = 8KB -> 24KB staging
//   <= 36KB epilogue overlay => LDS 36096 unchanged => 4 blocks/CU.
// Per iter: frag ds_reads -> barrier#1 (buffers consumed by ALL waves) ->
// issue next-tile X+W DMA -> cvt_pk_bf16 -> 16 MFMA -> barrier#2 (drains
// DMA aged by cvt+MFMA; X is L2-hot via XCD co-location so latency ~200cy).
// No persistent register cost (cvt at read; W stays in LDS - the r13 spill
// is structurally gone). x is read once (33.5MB, 4x L2-reused) instead of
// prologue read+write+gemm read (67MB): prep shrinks to W cvt + mailbox
// zero (<2us). X fp32 swizzle: 128B rows, 8x16B slots, slot = blk^(r&7)
// (r10/r13-proven); W swizzle/DMA byte-identical to r15 (blk^(r&3)).
// Epilogue / scan / batched lookback / apply / nontemporal out and the
// XCD co-location decode are byte-identical to r15.

namespace {
constexpr int kB  = 8;
constexpr int kT  = 4096;
constexpr int kD  = 256;
constexpr int kH  = 256;

constexpr int TM  = 128;          // time rows per block
constexpr int TH  = 64;           // h cols per block (dual-W => 128 eff. N)
constexpr int BK  = 32;           // GEMM k tile (8 iters)
constexpr int kNT = kT / TM;      // 32 time-tiles per chain
constexpr int kNChain = kB * (kH / TH);   // 32 chains
constexpr int EPS = 66;           // epilogue LDS row stride (half)
} // namespace

typedef short s16x8 __attribute__((ext_vector_type(8)));
typedef short s16x4 __attribute__((ext_vector_type(4)));
typedef float f32x4 __attribute__((ext_vector_type(4)));

__device__ __forceinline__ short f2bf(float f) {
    union { float f; unsigned int u; } v; v.f = f;
    unsigned int r = v.u + 0x7fffu + ((v.u >> 16) & 1u);   // RNE
    return (short)(r >> 16);
}

// packed RNE f32x2 -> bf16x2 (low word = lo operand); same rounding as f2bf
__device__ __forceinline__ unsigned int cvt_pk_bf16(float lo, float hi) {
    unsigned int r;
    asm("v_cvt_pk_bf16_f32 %0, %1, %2" : "=v"(r) : "v"(lo), "v"(hi));
    return r;
}

__device__ __forceinline__ void load_lds16(const void* g, void* l) {
    __builtin_amdgcn_global_load_lds(
        (const __attribute__((address_space(1))) void*)g,
        (__attribute__((address_space(3))) void*)l, 16, 0, 0);
}

// ---------------------------------------------------------------------------
// Kernel 1 (tiny): fp32 -> bf16 for Wz, Wh; zero the 512 KB aggregate mailbox.
// ---------------------------------------------------------------------------
__global__ __launch_bounds__(256)
void prep(const float* __restrict__ Wz,
          const float* __restrict__ Wh,
          unsigned short* __restrict__ wzb,
          unsigned short* __restrict__ whb,
          float4* __restrict__ aggz)
{
    constexpr int W4 = kH * kD / 4;           // 16,384 each
    const int i = blockIdx.x * 256 + threadIdx.x;

    if (i >= 2 * W4) {                        // zero mailbox (32768 float4)
        float4 z; z.x = 0.f; z.y = 0.f; z.z = 0.f; z.w = 0.f;
        aggz[i - 2 * W4] = z;
        return;
    }
    const float* src; unsigned short* dst; int j;
    if (i < W4) { src = Wz; dst = wzb; j = i; }
    else        { src = Wh; dst = whb; j = i - W4; }
    const float4 v = ((const float4*)src)[j];
    s16x4 p;
    p[0] = f2bf(v.x); p[1] = f2bf(v.y); p[2] = f2bf(v.z); p[3] = f2bf(v.w);
    ((s16x4*)dst)[j] = p;
}

// ---------------------------------------------------------------------------
// Kernel 2: fp32-X DMA pipelined GEMM (2 barriers/iter, zero-register
// staging) + sigmoid + block aggregate + lookback + apply + out.
// Grid: 1024 blocks (XCD-swizzled 1-D), 4 waves, 4 blocks/CU.
// ---------------------------------------------------------------------------
__global__ __launch_bounds__(256, 4)
void gemm_scan_fused(const float* __restrict__ x,
                     const unsigned short* __restrict__ wzb,
                     const unsigned short* __restrict__ whb,
                     const float* __restrict__ bz,
                     const float* __restrict__ bh,
                     const float* __restrict__ h0,
                     unsigned long long* __restrict__ agg,  // [32][32][64]
                     float* __restrict__ out)
{
    // LDS: X [128][32] fp32 @0 (16K) | Wz [64][32] bf16 @16384 (4K) |
    // Wh @20480 (4K) -> staging ends 24576. Epilogue overlay: a_lds/b_lds
    // [128][66] half @0 (33792); sub_lds[4][64] float2 @33792; hs_lds[64]
    // @35840. Total 36096 B => 4 blocks/CU.
    __shared__ __align__(16) unsigned char smem[36096];
    __half* a_lds   = (__half*)smem;                 // [128][EPS]
    __half* b_lds   = a_lds + 128 * EPS;
    float2* sub_lds = (float2*)(smem + 33792);       // [4][64]
    float*  hs_lds  = (float*)(smem + 35840);        // [64]

    const int tid  = threadIdx.x;
    const int lane = tid & 63;
    const int wv   = tid >> 6;
    const int ln15 = lane & 15;
    const int quad = lane >> 4;
    const int wr0  = (wv & 1) * 64;
    const int wc0  = (wv >> 1) * 32;

    // XCD co-location decode: the 4 col-groups of one (b,t) share id%8
    // (=> same XCD, shared X tile in that XCD's L2). Bijective over 1024.
    const int id  = blockIdx.x;
    const int r8  = id & 7;
    const int q   = id >> 3;
    const int cg  = q & 3;                   // col-group 0..3
    const int bt  = (q >> 2) * 8 + r8;       // 0..255
    const int b   = bt >> 5;
    const int t   = bt & 31;                 // time-tile in chain
    const int chain = b * 4 + cg;            // 0..31
    const int col0  = cg * TH;
    const int row0  = b * kT + t * TM;       // global BT row of tile top

    // X DMA geometry (128B fp32 rows, 8 slots of 16B): per 1KB instr,
    // 8 rows x 8 slots. lane covers row seg*8 + (lane>>3), LDS slot
    // (lane&7); fetched global 16B block = slot ^ (row&7) = (lane&7)^srow.
    const int srow8 = lane >> 3;             // 0..7
    const int sw8   = (lane & 7) ^ srow8;    // swizzled global block (x)
    // W DMA geometry (64B bf16 rows, 4 slots of 16B): per 1KB instr,
    // 16 rows x 4 slots. lane covers row wv*16 + (lane>>2), slot lane&3;
    // fetched global block = (lane&3) ^ (row&3).
    const int wrow  = lane >> 2;             // 0..15
    const int wfet  = (lane & 3) ^ (wrow & 3);

    f32x4 accZ[4][2] = {};
    f32x4 accU[4][2] = {};

    // ---- prologue: DMA X(0) + W(0)
    #pragma unroll
    for (int s2 = 0; s2 < 4; ++s2) {
        const int seg = wv * 4 + s2;                 // 0..15, rows seg*8..+8
        load_lds16(x + (size_t)(row0 + seg * 8 + srow8) * kD + sw8 * 4,
                   smem + seg * 1024);
    }
    load_lds16(wzb + (size_t)(col0 + wv * 16 + wrow) * kD + wfet * 8,
               smem + 16384 + wv * 1024);
    load_lds16(whb + (size_t)(col0 + wv * 16 + wrow) * kD + wfet * 8,
               smem + 20480 + wv * 1024);
    __syncthreads();   // drains tile-0 DMA (exposed once)

    // ---- K loop: 8 iters of BK=32; frag-read -> barrier -> issue DMA ->
    // cvt+MFMA -> barrier (DMA aged by cvt+MFMA, L2-hot via co-location)
    #pragma unroll
    for (int k = 0; k < 8; ++k) {
        // fragment reads (fp32 X + bf16 W) from the single buffers
        const float* Xc = (const float*)smem;
        const unsigned short* Wzc = (const unsigned short*)(smem + 16384);
        const unsigned short* Whc = Wzc + 2048;      // +4096 B
        f32x4 xf0[4], xf1[4];
        s16x8 bzf[2], bhf[2];
        #pragma unroll
        for (int mt = 0; mt < 4; ++mt) {
            const int r = wr0 + mt * 16 + ln15;
            const int m = r & 7;
            xf0[mt] = *(const f32x4*)&Xc[r * 32 + (((2 * quad) ^ m) << 2)];
            xf1[mt] = *(const f32x4*)&Xc[r * 32 + (((2 * quad + 1) ^ m) << 2)];
        }
        #pragma unroll
        for (int nt = 0; nt < 2; ++nt) {
            const int rw = wc0 + nt * 16 + ln15;
            const int so = (quad ^ (rw & 3)) << 3;
            bzf[nt] = *(const s16x8*)&Wzc[rw * 32 + so];
            bhf[nt] = *(const s16x8*)&Whc[rw * 32 + so];
        }
        __syncthreads();   // barrier #1: all waves consumed the buffers

        if (k < 7) {
            const int o = (k + 1) * BK;
            #pragma unroll
            for (int s2 = 0; s2 < 4; ++s2) {
                const int seg = wv * 4 + s2;
                load_lds16(
                    x + (size_t)(row0 + seg * 8 + srow8) * kD + o + sw8 * 4,
                    smem + seg * 1024);
            }
            load_lds16(wzb + (size_t)(col0 + wv * 16 + wrow) * kD + o + wfet * 8,
                       smem + 16384 + wv * 1024);
            load_lds16(whb + (size_t)(col0 + wv * 16 + wrow) * kD + o + wfet * 8,
                       smem + 20480 + wv * 1024);
        }
        __builtin_amdgcn_sched_barrier(0);   // keep DMA issues above compute

        s16x8 af[4];
        #pragma unroll
        for (int mt = 0; mt < 4; ++mt) {
            union { unsigned int u[4]; s16x8 v; } pk;
            pk.u[0] = cvt_pk_bf16(xf0[mt][0], xf0[mt][1]);
            pk.u[1] = cvt_pk_bf16(xf0[mt][2], xf0[mt][3]);
            pk.u[2] = cvt_pk_bf16(xf1[mt][0], xf1[mt][1]);
            pk.u[3] = cvt_pk_bf16(xf1[mt][2], xf1[mt][3]);
            af[mt] = pk.v;
        }
        __builtin_amdgcn_s_setprio(1);
        #pragma unroll
        for (int mt = 0; mt < 4; ++mt) {
            #pragma unroll
            for (int nt = 0; nt < 2; ++nt) {
                accZ[mt][nt] = __builtin_amdgcn_mfma_f32_16x16x32_bf16(
                    af[mt], bzf[nt], accZ[mt][nt], 0, 0, 0);
                accU[mt][nt] = __builtin_amdgcn_mfma_f32_16x16x32_bf16(
                    af[mt], bhf[nt], accU[mt][nt], 0, 0, 0);
            }
        }
        __builtin_amdgcn_s_setprio(0);
        __syncthreads();   // barrier #2: next tile's DMA landed
    }

    // ---- epilogue: sigmoid; a/bb -> LDS fp16 (C/D: col=ln15, row=quad*4+r)
    #pragma unroll
    for (int nt = 0; nt < 2; ++nt) {
        const int col = col0 + wc0 + nt * 16 + ln15;
        const int lc  = wc0 + nt * 16 + ln15;
        const float bzv = bz[col];
        const float bhv = bh[col];
        #pragma unroll
        for (int mt = 0; mt < 4; ++mt) {
            const int rb = wr0 + mt * 16 + quad * 4;
            #pragma unroll
            for (int r = 0; r < 4; ++r) {
                const float z = accZ[mt][nt][r] + bzv;
                const float g = 1.0f / (1.0f + __expf(-z));
                const float u = accU[mt][nt][r] + bhv;
                a_lds[(rb + r) * EPS + lc] = __float2half_rn(1.0f - g);
                b_lds[(rb + r) * EPS + lc] = __float2half_rn(g * u);
            }
        }
    }
    __syncthreads();

    // ---- sub-chunk (32-row) affine summaries: thread (s,h)
    const int s = tid >> 6;
    const int h = tid & 63;
    {
        float A = 1.0f, Bv = 0.0f;
        #pragma unroll 8
        for (int r = s * 32; r < s * 32 + 32; ++r) {
            const float a  = __half2float(a_lds[r * EPS + h]);
            const float bb = __half2float(b_lds[r * EPS + h]);
            Bv = fmaf(a, Bv, bb);
            A *= a;
        }
        float2 o; o.x = A; o.y = Bv;
        sub_lds[s * 64 + h] = o;
    }
    __syncthreads();

    // ---- publish block aggregate + batched lookback (one lane per h)
    if (tid < 64) {
        float A = 1.0f, Bv = 0.0f;
        #pragma unroll
        for (int s2 = 0; s2 < 4; ++s2) {
            const float2 g = sub_lds[s2 * 64 + tid];
            Bv = fmaf(g.x, Bv, g.y);
            A *= g.x;
        }
        union { float2 f; unsigned long long u; } pk;
        pk.f.x = A; pk.f.y = Bv;
        pk.u |= 1ull;                         // never 0 => unambiguous flag
        __hip_atomic_store(&agg[(size_t)(chain * kNT + t) * 64 + tid], pk.u,
                           __ATOMIC_RELAXED, __HIP_MEMORY_SCOPE_AGENT);

        // lookback over predecessors 0..t-1, 8 at a time (independent loads,
        // one L2/L3 latency per batch; fold strictly in order).
        float hs = h0[(size_t)b * kH + col0 + tid];
        for (int j0 = 0; j0 < t; j0 += 8) {
            const int nb = (t - j0 < 8) ? (t - j0) : 8;
            unsigned long long u[8];
            #pragma unroll
            for (int q2 = 0; q2 < 8; ++q2)
                if (q2 < nb)
                    u[q2] = __hip_atomic_load(
                        &agg[(size_t)(chain * kNT + j0 + q2) * 64 + tid],
                        __ATOMIC_RELAXED, __HIP_MEMORY_SCOPE_AGENT);
            #pragma unroll
            for (int q2 = 0; q2 < 8; ++q2) {
                if (q2 < nb) {
                    while (u[q2] == 0ull)
                        u[q2] = __hip_atomic_load(
                            &agg[(size_t)(chain * kNT + j0 + q2) * 64 + tid],
                            __ATOMIC_RELAXED, __HIP_MEMORY_SCOPE_AGENT);
                    union { unsigned long long u; float2 f; } qk; qk.u = u[q2];
                    hs = fmaf(qk.f.x, hs, qk.f.y);
                }
            }
        }
        hs_lds[tid] = hs;
    }
    __syncthreads();

    // ---- apply recurrence: thread (s,h) does its 32 rows, writes out
    {
        float hv = hs_lds[h];
        #pragma unroll
        for (int s2 = 0; s2 < s; ++s2) {
            const float2 g = sub_lds[s2 * 64 + h];
            hv = fmaf(g.x, hv, g.y);
        }
        #pragma unroll 8
        for (int r = 0; r < 32; ++r) {
            const int lr = s * 32 + r;
            const float a  = __half2float(a_lds[lr * EPS + h]);
            const float bb = __half2float(b_lds[lr * EPS + h]);
            hv = fmaf(a, hv, bb);
            __builtin_nontemporal_store(hv, &out[(size_t)(row0 + lr) * kH + col0 + h]);
        }
    }
}

extern "C" void kernel_launch(void* const* d_in, const int* in_sizes, int n_in,
                              void* d_out, int out_size, void* d_ws, size_t ws_size,
                              hipStream_t stream)
{
    const float* x  = (const float*)d_in[0];
    const float* h0 = (const float*)d_in[1];
    const float* Wz = (const float*)d_in[2];
    const float* bz = (const float*)d_in[3];
    const float* Wh = (const float*)d_in[4];
    const float* bh = (const float*)d_in[5];
    float* out = (float*)d_out;

    // Workspace: wzb/whb 131K each | agg 512K  => ~0.8 MB.
    unsigned char* ws = (unsigned char*)d_ws;
    unsigned short* wzb = (unsigned short*)ws;   ws += (size_t)kH * kD * 2;
    unsigned short* whb = (unsigned short*)ws;   ws += (size_t)kH * kD * 2;
    unsigned long long* agg = (unsigned long long*)ws;

    constexpr int PREP_ITEMS = 2 * (kH * kD / 4)
                             + kNChain * kNT * TH * 8 / 16;   // 65,536
    prep<<<PREP_ITEMS / 256, 256, 0, stream>>>(
        Wz, Wh, wzb, whb, (float4*)agg);
    gemm_scan_fused<<<kNChain * kNT, 256, 0, stream>>>(
        x, wzb, whb, bz, bh, h0, agg, out);
}

// Round 10
// 116.713 us; speedup vs baseline: 1.1905x; 1.1905x over previous
//
#include <hip/hip_runtime.h>
#include <hip/hip_fp16.h>

// MinGRU single-pass fused pipeline, round 17. Goal: r15's proven
// single-barrier deep pipeline (gemm ~33us) WITHOUT the 9us x->bf16
// prologue, and WITHOUT the register spills that killed r9/r13/r16.
//  - X staged fp32 via global_load_lds, LDS double-buffered:
//    2 x [128][32] fp32 = 32KB <= 36KB epilogue overlay => LDS 36096
//    unchanged => 4 blocks/CU. Zero staging registers.
//  - W fragments direct global->reg (bf16 from prep-converted wzb/whb),
//    loaded AND consumed inside the same iteration - never live across a
//    barrier (16 regs). W is L2-hot in every XCD (all 1024 blocks read it).
//  - cvt_pk_bf16 folded per-mt: fp32 transients are 8 regs at a time,
//    af is 4 regs live. Peak ~= 64 AGPR + ~56 arch < 128 cap.
//  - Issue order per iter: W reg-loads FIRST, then X DMA(k+1) -> the
//    compiler's pre-MFMA wait is vmcnt(4) (W only); the DMA stays in
//    flight across frag-read+cvt+MFMA and drains at the single
//    end-of-iter barrier (issue-early/drain-late, full aging).
// x is read once (33.5MB fp32, 4x L2-reused via XCD co-location) - no xb
// workspace round-trip; prep shrinks to W cvt + mailbox zero (<2us).
// Epilogue / scan / batched lookback / apply / nontemporal out and the
// XCD co-location decode are byte-identical to r15.
// Tripwire: WRITE > 60MB = spill => revert to r15 next round.

namespace {
constexpr int kB  = 8;
constexpr int kT  = 4096;
constexpr int kD  = 256;
constexpr int kH  = 256;

constexpr int TM  = 128;          // time rows per block
constexpr int TH  = 64;           // h cols per block (dual-W => 128 eff. N)
constexpr int BK  = 32;           // GEMM k tile (8 iters)
constexpr int kNT = kT / TM;      // 32 time-tiles per chain
constexpr int kNChain = kB * (kH / TH);   // 32 chains
constexpr int EPS = 66;           // epilogue LDS row stride (half)
} // namespace

typedef short s16x8 __attribute__((ext_vector_type(8)));
typedef short s16x4 __attribute__((ext_vector_type(4)));
typedef float f32x4 __attribute__((ext_vector_type(4)));

__device__ __forceinline__ short f2bf(float f) {
    union { float f; unsigned int u; } v; v.f = f;
    unsigned int r = v.u + 0x7fffu + ((v.u >> 16) & 1u);   // RNE
    return (short)(r >> 16);
}

// packed RNE f32x2 -> bf16x2 (low word = lo operand); same rounding as f2bf
__device__ __forceinline__ unsigned int cvt_pk_bf16(float lo, float hi) {
    unsigned int r;
    asm("v_cvt_pk_bf16_f32 %0, %1, %2" : "=v"(r) : "v"(lo), "v"(hi));
    return r;
}

__device__ __forceinline__ void load_lds16(const void* g, void* l) {
    __builtin_amdgcn_global_load_lds(
        (const __attribute__((address_space(1))) void*)g,
        (__attribute__((address_space(3))) void*)l, 16, 0, 0);
}

// ---------------------------------------------------------------------------
// Kernel 1 (tiny): fp32 -> bf16 for Wz, Wh; zero the 512 KB aggregate mailbox.
// ---------------------------------------------------------------------------
__global__ __launch_bounds__(256)
void prep(const float* __restrict__ Wz,
          const float* __restrict__ Wh,
          unsigned short* __restrict__ wzb,
          unsigned short* __restrict__ whb,
          float4* __restrict__ aggz)
{
    constexpr int W4 = kH * kD / 4;           // 16,384 each
    const int i = blockIdx.x * 256 + threadIdx.x;

    if (i >= 2 * W4) {                        // zero mailbox (32768 float4)
        float4 z; z.x = 0.f; z.y = 0.f; z.z = 0.f; z.w = 0.f;
        aggz[i - 2 * W4] = z;
        return;
    }
    const float* src; unsigned short* dst; int j;
    if (i < W4) { src = Wz; dst = wzb; j = i; }
    else        { src = Wh; dst = whb; j = i - W4; }
    const float4 v = ((const float4*)src)[j];
    s16x4 p;
    p[0] = f2bf(v.x); p[1] = f2bf(v.y); p[2] = f2bf(v.z); p[3] = f2bf(v.w);
    ((s16x4*)dst)[j] = p;
}

// ---------------------------------------------------------------------------
// Kernel 2: fp32-X dbuf DMA + W-in-reg single-barrier GEMM + sigmoid +
// block aggregate + lookback + apply + out. Grid: 1024 blocks
// (XCD-swizzled 1-D), 4 waves, 4 blocks/CU.
// ---------------------------------------------------------------------------
__global__ __launch_bounds__(256, 4)
void gemm_scan_fused(const float* __restrict__ x,
                     const unsigned short* __restrict__ wzb,
                     const unsigned short* __restrict__ whb,
                     const float* __restrict__ bz,
                     const float* __restrict__ bh,
                     const float* __restrict__ h0,
                     unsigned long long* __restrict__ agg,  // [32][32][64]
                     float* __restrict__ out)
{
    // LDS: X buf0 [128][32] fp32 @0 (16K) | X buf1 @16384 (16K) -> 32768.
    // Epilogue overlay: a_lds/b_lds [128][66] half @0 (33792);
    // sub_lds[4][64] float2 @33792; hs_lds[64] @35840. Total 36096 B.
    __shared__ __align__(16) unsigned char smem[36096];
    __half* a_lds   = (__half*)smem;                 // [128][EPS]
    __half* b_lds   = a_lds + 128 * EPS;
    float2* sub_lds = (float2*)(smem + 33792);       // [4][64]
    float*  hs_lds  = (float*)(smem + 35840);        // [64]

    const int tid  = threadIdx.x;
    const int lane = tid & 63;
    const int wv   = tid >> 6;
    const int ln15 = lane & 15;
    const int quad = lane >> 4;
    const int wr0  = (wv & 1) * 64;
    const int wc0  = (wv >> 1) * 32;

    // XCD co-location decode: the 4 col-groups of one (b,t) share id%8
    // (=> same XCD, shared X tile in that XCD's L2). Bijective over 1024.
    const int id  = blockIdx.x;
    const int r8  = id & 7;
    const int q   = id >> 3;
    const int cg  = q & 3;                   // col-group 0..3
    const int bt  = (q >> 2) * 8 + r8;       // 0..255
    const int b   = bt >> 5;
    const int t   = bt & 31;                 // time-tile in chain
    const int chain = b * 4 + cg;            // 0..31
    const int col0  = cg * TH;
    const int row0  = b * kT + t * TM;       // global BT row of tile top

    // X DMA geometry (128B fp32 rows, 8 slots of 16B): per 1KB instr,
    // 8 rows x 8 slots. lane covers row seg*8 + (lane>>3), LDS slot
    // (lane&7); fetched global 16B block = slot ^ (row&7) = (lane&7)^srow.
    const int srow8 = lane >> 3;             // 0..7
    const int sw8   = (lane & 7) ^ srow8;    // swizzled global block (x)

    // W fragment bases (direct-to-reg, per-iter load+consume).
    const unsigned short* wzbase =
        wzb + (size_t)(col0 + wc0 + ln15) * kD + quad * 8;
    const unsigned short* whbase =
        whb + (size_t)(col0 + wc0 + ln15) * kD + quad * 8;

    f32x4 accZ[4][2] = {};
    f32x4 accU[4][2] = {};

    // ---- prologue: DMA X(0) into buf0
    #pragma unroll
    for (int s2 = 0; s2 < 4; ++s2) {
        const int seg = wv * 4 + s2;                 // 0..15, rows seg*8..+8
        load_lds16(x + (size_t)(row0 + seg * 8 + srow8) * kD + sw8 * 4,
                   smem + seg * 1024);
    }
    __syncthreads();   // drains tile-0 DMA (exposed once)

    // ---- K loop: 8 iters of BK=32, ONE barrier each
    #pragma unroll
    for (int k = 0; k < 8; ++k) {
        const int cur = k & 1;
        const int o = k * BK;
        // W frag loads FIRST (so the pre-MFMA wait is vmcnt(4): W only,
        // DMA stays in flight), then next-tile X DMA.
        s16x8 bzf[2], bhf[2];
        #pragma unroll
        for (int nt = 0; nt < 2; ++nt) {
            bzf[nt] = *(const s16x8*)(wzbase + (size_t)nt * 16 * kD + o);
            bhf[nt] = *(const s16x8*)(whbase + (size_t)nt * 16 * kD + o);
        }
        if (k < 7) {
            const int on = o + BK;
            #pragma unroll
            for (int s2 = 0; s2 < 4; ++s2) {
                const int seg = wv * 4 + s2;
                load_lds16(
                    x + (size_t)(row0 + seg * 8 + srow8) * kD + on + sw8 * 4,
                    smem + (cur ^ 1) * 16384 + seg * 1024);
            }
        }
        __builtin_amdgcn_sched_barrier(0);   // keep issues above compute

        // per-mt: fp32 frag read -> cvt -> 4 MFMA (small register windows)
        const float* Xc = (const float*)(smem + cur * 16384);
        #pragma unroll
        for (int mt = 0; mt < 4; ++mt) {
            const int r = wr0 + mt * 16 + ln15;
            const int m = r & 7;
            const f32x4 f0 = *(const f32x4*)&Xc[r * 32 + (((2 * quad) ^ m) << 2)];
            const f32x4 f1 = *(const f32x4*)&Xc[r * 32 + (((2 * quad + 1) ^ m) << 2)];
            union { unsigned int u[4]; s16x8 v; } pk;
            pk.u[0] = cvt_pk_bf16(f0[0], f0[1]);
            pk.u[1] = cvt_pk_bf16(f0[2], f0[3]);
            pk.u[2] = cvt_pk_bf16(f1[0], f1[1]);
            pk.u[3] = cvt_pk_bf16(f1[2], f1[3]);
            const s16x8 af = pk.v;
            __builtin_amdgcn_s_setprio(1);
            #pragma unroll
            for (int nt = 0; nt < 2; ++nt) {
                accZ[mt][nt] = __builtin_amdgcn_mfma_f32_16x16x32_bf16(
                    af, bzf[nt], accZ[mt][nt], 0, 0, 0);
                accU[mt][nt] = __builtin_amdgcn_mfma_f32_16x16x32_bf16(
                    af, bhf[nt], accU[mt][nt], 0, 0, 0);
            }
            __builtin_amdgcn_s_setprio(0);
        }
        __syncthreads();   // reads of buf[cur] done; drains X DMA(k+1)
    }

    // ---- epilogue: sigmoid; a/bb -> LDS fp16 (C/D: col=ln15, row=quad*4+r)
    #pragma unroll
    for (int nt = 0; nt < 2; ++nt) {
        const int col = col0 + wc0 + nt * 16 + ln15;
        const int lc  = wc0 + nt * 16 + ln15;
        const float bzv = bz[col];
        const float bhv = bh[col];
        #pragma unroll
        for (int mt = 0; mt < 4; ++mt) {
            const int rb = wr0 + mt * 16 + quad * 4;
            #pragma unroll
            for (int r = 0; r < 4; ++r) {
                const float z = accZ[mt][nt][r] + bzv;
                const float g = 1.0f / (1.0f + __expf(-z));
                const float u = accU[mt][nt][r] + bhv;
                a_lds[(rb + r) * EPS + lc] = __float2half_rn(1.0f - g);
                b_lds[(rb + r) * EPS + lc] = __float2half_rn(g * u);
            }
        }
    }
    __syncthreads();

    // ---- sub-chunk (32-row) affine summaries: thread (s,h)
    const int s = tid >> 6;
    const int h = tid & 63;
    {
        float A = 1.0f, Bv = 0.0f;
        #pragma unroll 8
        for (int r = s * 32; r < s * 32 + 32; ++r) {
            const float a  = __half2float(a_lds[r * EPS + h]);
            const float bb = __half2float(b_lds[r * EPS + h]);
            Bv = fmaf(a, Bv, bb);
            A *= a;
        }
        float2 o; o.x = A; o.y = Bv;
        sub_lds[s * 64 + h] = o;
    }
    __syncthreads();

    // ---- publish block aggregate + batched lookback (one lane per h)
    if (tid < 64) {
        float A = 1.0f, Bv = 0.0f;
        #pragma unroll
        for (int s2 = 0; s2 < 4; ++s2) {
            const float2 g = sub_lds[s2 * 64 + tid];
            Bv = fmaf(g.x, Bv, g.y);
            A *= g.x;
        }
        union { float2 f; unsigned long long u; } pk;
        pk.f.x = A; pk.f.y = Bv;
        pk.u |= 1ull;                         // never 0 => unambiguous flag
        __hip_atomic_store(&agg[(size_t)(chain * kNT + t) * 64 + tid], pk.u,
                           __ATOMIC_RELAXED, __HIP_MEMORY_SCOPE_AGENT);

        // lookback over predecessors 0..t-1, 8 at a time (independent loads,
        // one L2/L3 latency per batch; fold strictly in order).
        float hs = h0[(size_t)b * kH + col0 + tid];
        for (int j0 = 0; j0 < t; j0 += 8) {
            const int nb = (t - j0 < 8) ? (t - j0) : 8;
            unsigned long long u[8];
            #pragma unroll
            for (int q2 = 0; q2 < 8; ++q2)
                if (q2 < nb)
                    u[q2] = __hip_atomic_load(
                        &agg[(size_t)(chain * kNT + j0 + q2) * 64 + tid],
                        __ATOMIC_RELAXED, __HIP_MEMORY_SCOPE_AGENT);
            #pragma unroll
            for (int q2 = 0; q2 < 8; ++q2) {
                if (q2 < nb) {
                    while (u[q2] == 0ull)
                        u[q2] = __hip_atomic_load(
                            &agg[(size_t)(chain * kNT + j0 + q2) * 64 + tid],
                            __ATOMIC_RELAXED, __HIP_MEMORY_SCOPE_AGENT);
                    union { unsigned long long u; float2 f; } qk; qk.u = u[q2];
                    hs = fmaf(qk.f.x, hs, qk.f.y);
                }
            }
        }
        hs_lds[tid] = hs;
    }
    __syncthreads();

    // ---- apply recurrence: thread (s,h) does its 32 rows, writes out
    {
        float hv = hs_lds[h];
        #pragma unroll
        for (int s2 = 0; s2 < s; ++s2) {
            const float2 g = sub_lds[s2 * 64 + h];
            hv = fmaf(g.x, hv, g.y);
        }
        #pragma unroll 8
        for (int r = 0; r < 32; ++r) {
            const int lr = s * 32 + r;
            const float a  = __half2float(a_lds[lr * EPS + h]);
            const float bb = __half2float(b_lds[lr * EPS + h]);
            hv = fmaf(a, hv, bb);
            __builtin_nontemporal_store(hv, &out[(size_t)(row0 + lr) * kH + col0 + h]);
        }
    }
}

extern "C" void kernel_launch(void* const* d_in, const int* in_sizes, int n_in,
                              void* d_out, int out_size, void* d_ws, size_t ws_size,
                              hipStream_t stream)
{
    const float* x  = (const float*)d_in[0];
    const float* h0 = (const float*)d_in[1];
    const float* Wz = (const float*)d_in[2];
    const float* bz = (const float*)d_in[3];
    const float* Wh = (const float*)d_in[4];
    const float* bh = (const float*)d_in[5];
    float* out = (float*)d_out;

    // Workspace: wzb/whb 131K each | agg 512K  => ~0.8 MB.
    unsigned char* ws = (unsigned char*)d_ws;
    unsigned short* wzb = (unsigned short*)ws;   ws += (size_t)kH * kD * 2;
    unsigned short* whb = (unsigned short*)ws;   ws += (size_t)kH * kD * 2;
    unsigned long long* agg = (unsigned long long*)ws;

    constexpr int PREP_ITEMS = 2 * (kH * kD / 4)
                             + kNChain * kNT * TH * 8 / 16;   // 65,536
    prep<<<PREP_ITEMS / 256, 256, 0, stream>>>(
        Wz, Wh, wzb, whb, (float4*)agg);
    gemm_scan_fused<<<kNChain * kNT, 256, 0, stream>>>(
        x, wzb, whb, bz, bh, h0, agg, out);
}

// Round 11
// 112.942 us; speedup vs baseline: 1.2302x; 1.0334x over previous
//
#include <hip/hip_runtime.h>
#include <hip/hip_fp16.h>

// MinGRU single-pass fused pipeline, FINAL = round 10 (the session-best
// 114.16us kernel), restored verbatim. Session summary of the GEMM-phase
// search: r8 baseline (in-kernel x cvt, 45.5us gemm) -> r10 adds the XCD
// co-location block swizzle (4 col-group blocks sharing an X tile land on
// one XCD's L2: FETCH 68->~40MB, gemm ~40us, total 114.2 = best). Deeper
// pipelines (r9/r11/r13/r15/r16/r17) either hit the 128-reg unified cap
// (spill => +90-130MB scratch traffic), lost residency (3/CU), lost
// coalescing (direct-global frags), or duplicated scan work (TM=64); the
// one clean win (r15: dbuf DMA, gemm ~33us) was exactly cancelled by its
// required 9us x->bf16 prologue. Totals across all structural variants
// cluster at 114-117us: the measured region is dominated by fixed harness
// costs (256MB workspace re-poison fill ~44us @ 77% HBM peak + restore +
// gaps ~= 75-80us), so the remaining controllable delta is below noise.
// Swizzle scheme: row = 8 x 16B blocks; global block b of row r lives at
// LDS slot b ^ (r & 7).

namespace {
constexpr int kB  = 8;
constexpr int kT  = 4096;
constexpr int kD  = 256;
constexpr int kH  = 256;
constexpr int kBT = kB * kT;

constexpr int TM  = 128;          // time rows per block
constexpr int TH  = 64;           // h cols per block (dual-W => 128 eff. N)
constexpr int BK  = 64;           // GEMM k tile
constexpr int kNT = kT / TM;      // 32 time-tiles per chain
constexpr int kNChain = kB * (kH / TH);   // 32 chains
constexpr int EPS = 66;           // epilogue LDS row stride (half)
} // namespace

typedef short s16x8 __attribute__((ext_vector_type(8)));
typedef short s16x4 __attribute__((ext_vector_type(4)));
typedef float f32x4 __attribute__((ext_vector_type(4)));

__device__ __forceinline__ short f2bf(float f) {
    union { float f; unsigned int u; } v; v.f = f;
    unsigned int r = v.u + 0x7fffu + ((v.u >> 16) & 1u);   // RNE
    return (short)(r >> 16);
}

// packed RNE f32x2 -> bf16x2 (low word = lo operand); same rounding as f2bf
__device__ __forceinline__ unsigned int cvt_pk_bf16(float lo, float hi) {
    unsigned int r;
    asm("v_cvt_pk_bf16_f32 %0, %1, %2" : "=v"(r) : "v"(lo), "v"(hi));
    return r;
}

__device__ __forceinline__ void load_lds16(const void* g, void* l) {
    __builtin_amdgcn_global_load_lds(
        (const __attribute__((address_space(1))) void*)g,
        (__attribute__((address_space(3))) void*)l, 16, 0, 0);
}

// ---------------------------------------------------------------------------
// Kernel 1 (tiny): fp32 -> bf16 for Wz, Wh; zero the 512 KB aggregate mailbox.
// ---------------------------------------------------------------------------
__global__ __launch_bounds__(256)
void prep(const float* __restrict__ Wz,
          const float* __restrict__ Wh,
          unsigned short* __restrict__ wzb,
          unsigned short* __restrict__ whb,
          float4* __restrict__ aggz)
{
    constexpr int W4 = kH * kD / 4;           // 16,384 each
    const int i = blockIdx.x * 256 + threadIdx.x;

    if (i >= 2 * W4) {                        // zero mailbox (32768 float4)
        float4 z; z.x = 0.f; z.y = 0.f; z.z = 0.f; z.w = 0.f;
        aggz[i - 2 * W4] = z;
        return;
    }
    const float* src; unsigned short* dst; int j;
    if (i < W4) { src = Wz; dst = wzb; j = i; }
    else        { src = Wh; dst = whb; j = i - W4; }
    const float4 v = ((const float4*)src)[j];
    s16x4 p;
    p[0] = f2bf(v.x); p[1] = f2bf(v.y); p[2] = f2bf(v.z); p[3] = f2bf(v.w);
    ((s16x4*)dst)[j] = p;
}

// ---------------------------------------------------------------------------
// Kernel 2: fused convert + GEMM + sigmoid + block aggregate + lookback +
// apply + out. Grid: 1024 blocks (XCD-swizzled 1-D). 4 waves/block,
// 4 blocks/CU (all 1024 resident).
// ---------------------------------------------------------------------------
__global__ __launch_bounds__(256, 4)
void gemm_scan_fused(const float* __restrict__ x,
                     const unsigned short* __restrict__ wzb,
                     const unsigned short* __restrict__ whb,
                     const float* __restrict__ bz,
                     const float* __restrict__ bh,
                     const float* __restrict__ h0,
                     unsigned long long* __restrict__ agg,  // [32 chains][32 t][64 h]
                     float* __restrict__ out)
{
    // LDS: staging Xs[128][64] | Wzs[64][64] | Whs[64][64] ushort (32KB,
    // XOR-swizzled 16B blocks), overlaid after the K loop by a_lds/b_lds
    // [128][66] half; + sub_lds[4][64] float2 @33792 ; + hs_lds[64] @35840.
    __shared__ __align__(16) unsigned char smem[36096];
    unsigned short* Xs  = (unsigned short*)smem;
    unsigned short* Wzs = Xs  + 128 * 64;
    unsigned short* Whs = Wzs + 64 * 64;
    __half* a_lds   = (__half*)smem;                 // [128][EPS]
    __half* b_lds   = a_lds + 128 * EPS;
    float2* sub_lds = (float2*)(smem + 33792);       // [4][64]
    float*  hs_lds  = (float*)(smem + 35840);        // [64]

    const int tid  = threadIdx.x;
    const int lane = tid & 63;
    const int wv   = tid >> 6;
    const int ln15 = lane & 15;
    const int quad = lane >> 4;
    const int wr0  = (wv & 1) * 64;
    const int wc0  = (wv >> 1) * 32;

    // XCD co-location decode: the 4 col-groups of one (b,t) share id%8
    // (=> same XCD, shared X tile in that XCD's L2). Bijective over 1024.
    const int id  = blockIdx.x;
    const int r8  = id & 7;
    const int q   = id >> 3;
    const int cg  = q & 3;                   // col-group 0..3
    const int bt  = (q >> 2) * 8 + r8;       // 0..255
    const int b   = bt >> 5;
    const int t   = bt & 31;                 // time-tile in chain
    const int chain = b * 4 + cg;            // 0..31
    const int col0  = cg * TH;
    const int row0  = b * kT + t * TM;       // global BT row of tile top

    // W staging geometry (DMA path): segments of 8 rows x 128B; lane covers
    // row seg*8 + (lane>>3), LDS 16B slot (lane&7); fetched global block =
    // slot ^ srow since (abs row)&7 == srow.
    const int srow = lane >> 3;              // 0..7
    const int swslot = (lane & 7) ^ srow;    // swizzled global 16B block

    f32x4 accZ[4][2] = {};
    f32x4 accU[4][2] = {};

    for (int k0 = 0; k0 < kD; k0 += BK) {
        // W: async DMA first so it flies under the X reg-staging.
        #pragma unroll
        for (int s = 0; s < 2; ++s) {
            const int seg = wv * 2 + s;                  // 0..7
            const int m = seg * 8 + srow;                // 0..63
            load_lds16(wzb + (size_t)(col0 + m) * kD + k0 + swslot * 8,
                       Wzs + seg * 512);
            load_lds16(whb + (size_t)(col0 + m) * kD + k0 + swslot * 8,
                       Whs + seg * 512);
        }
        // X: fp32 global -> bf16 regs -> swizzled LDS. Thread covers 4 of the
        // 1024 16B-bf16 blocks: bi = j*256+tid, r = bi>>3 (0..127), blk = bi&7.
        // Per instr the wave touches 8 rows x full 256B k-width: coalesced.
        #pragma unroll
        for (int j = 0; j < 4; ++j) {
            const int bi  = j * 256 + tid;
            const int r   = bi >> 3;
            const int blk = bi & 7;
            const float* src = x + (size_t)(row0 + r) * kD + k0 + blk * 8;
            const float4 v0 = *(const float4*)src;
            const float4 v1 = *(const float4*)(src + 4);
            union { unsigned int u[4]; s16x8 v; } pk;
            pk.u[0] = cvt_pk_bf16(v0.x, v0.y);
            pk.u[1] = cvt_pk_bf16(v0.z, v0.w);
            pk.u[2] = cvt_pk_bf16(v1.x, v1.y);
            pk.u[3] = cvt_pk_bf16(v1.z, v1.w);
            *(s16x8*)&Xs[r * 64 + ((blk ^ (r & 7)) << 3)] = pk.v;
        }
        __syncthreads();   // drain DMA + ds_writes

        #pragma unroll
        for (int kk = 0; kk < BK; kk += 32) {
            const int bblk = (kk >> 3) + quad;           // global 16B block 0..7
            s16x8 af[4], bzf[2], buf[2];
            #pragma unroll
            for (int mt = 0; mt < 4; ++mt) {
                const int r = wr0 + mt * 16 + ln15;
                af[mt] = *(const s16x8*)&Xs[r * 64 + ((bblk ^ (r & 7)) << 3)];
            }
            #pragma unroll
            for (int nt = 0; nt < 2; ++nt) {
                const int rw = wc0 + nt * 16 + ln15;
                const int so = (bblk ^ (rw & 7)) << 3;
                bzf[nt] = *(const s16x8*)&Wzs[rw * 64 + so];
                buf[nt] = *(const s16x8*)&Whs[rw * 64 + so];
            }
            #pragma unroll
            for (int mt = 0; mt < 4; ++mt) {
                #pragma unroll
                for (int nt = 0; nt < 2; ++nt) {
                    accZ[mt][nt] = __builtin_amdgcn_mfma_f32_16x16x32_bf16(
                        af[mt], bzf[nt], accZ[mt][nt], 0, 0, 0);
                    accU[mt][nt] = __builtin_amdgcn_mfma_f32_16x16x32_bf16(
                        af[mt], buf[nt], accU[mt][nt], 0, 0, 0);
                }
            }
        }
        __syncthreads();   // all waves done with staging LDS
    }

    // ---- epilogue: sigmoid; a/bb -> LDS fp16 (C/D: col=ln15, row=quad*4+r)
    #pragma unroll
    for (int nt = 0; nt < 2; ++nt) {
        const int col = col0 + wc0 + nt * 16 + ln15;
        const int lc  = wc0 + nt * 16 + ln15;
        const float bzv = bz[col];
        const float bhv = bh[col];
        #pragma unroll
        for (int mt = 0; mt < 4; ++mt) {
            const int rb = wr0 + mt * 16 + quad * 4;
            #pragma unroll
            for (int r = 0; r < 4; ++r) {
                const float z = accZ[mt][nt][r] + bzv;
                const float g = 1.0f / (1.0f + __expf(-z));
                const float u = accU[mt][nt][r] + bhv;
                a_lds[(rb + r) * EPS + lc] = __float2half_rn(1.0f - g);
                b_lds[(rb + r) * EPS + lc] = __float2half_rn(g * u);
            }
        }
    }
    __syncthreads();

    // ---- sub-chunk (32-row) affine summaries: thread (s,h)
    const int s = tid >> 6;
    const int h = tid & 63;
    {
        float A = 1.0f, Bv = 0.0f;
        #pragma unroll 8
        for (int r = s * 32; r < s * 32 + 32; ++r) {
            const float a  = __half2float(a_lds[r * EPS + h]);
            const float bb = __half2float(b_lds[r * EPS + h]);
            Bv = fmaf(a, Bv, bb);
            A *= a;
        }
        float2 o; o.x = A; o.y = Bv;
        sub_lds[s * 64 + h] = o;
    }
    __syncthreads();

    // ---- publish block aggregate + batched lookback (one lane per h)
    if (tid < 64) {
        float A = 1.0f, Bv = 0.0f;
        #pragma unroll
        for (int s2 = 0; s2 < 4; ++s2) {
            const float2 g = sub_lds[s2 * 64 + tid];
            Bv = fmaf(g.x, Bv, g.y);
            A *= g.x;
        }
        union { float2 f; unsigned long long u; } pk;
        pk.f.x = A; pk.f.y = Bv;
        pk.u |= 1ull;                         // never 0 => unambiguous ready flag
        __hip_atomic_store(&agg[(size_t)(chain * kNT + t) * 64 + tid], pk.u,
                           __ATOMIC_RELAXED, __HIP_MEMORY_SCOPE_AGENT);

        // lookback over predecessors 0..t-1, 8 at a time (independent loads,
        // one L2/L3 latency per batch; fold strictly in order).
        float hs = h0[(size_t)b * kH + col0 + tid];
        for (int j0 = 0; j0 < t; j0 += 8) {
            const int nb = (t - j0 < 8) ? (t - j0) : 8;
            unsigned long long u[8];
            #pragma unroll
            for (int q2 = 0; q2 < 8; ++q2)
                if (q2 < nb)
                    u[q2] = __hip_atomic_load(
                        &agg[(size_t)(chain * kNT + j0 + q2) * 64 + tid],
                        __ATOMIC_RELAXED, __HIP_MEMORY_SCOPE_AGENT);
            #pragma unroll
            for (int q2 = 0; q2 < 8; ++q2) {
                if (q2 < nb) {
                    while (u[q2] == 0ull)
                        u[q2] = __hip_atomic_load(
                            &agg[(size_t)(chain * kNT + j0 + q2) * 64 + tid],
                            __ATOMIC_RELAXED, __HIP_MEMORY_SCOPE_AGENT);
                    union { unsigned long long u; float2 f; } qk; qk.u = u[q2];
                    hs = fmaf(qk.f.x, hs, qk.f.y);
                }
            }
        }
        hs_lds[tid] = hs;
    }
    __syncthreads();

    // ---- apply recurrence: thread (s,h) does its 32 rows, writes out
    {
        float hv = hs_lds[h];
        #pragma unroll
        for (int s2 = 0; s2 < s; ++s2) {
            const float2 g = sub_lds[s2 * 64 + h];
            hv = fmaf(g.x, hv, g.y);
        }
        #pragma unroll 8
        for (int r = 0; r < 32; ++r) {
            const int lr = s * 32 + r;
            const float a  = __half2float(a_lds[lr * EPS + h]);
            const float bb = __half2float(b_lds[lr * EPS + h]);
            hv = fmaf(a, hv, bb);
            __builtin_nontemporal_store(hv, &out[(size_t)(row0 + lr) * kH + col0 + h]);
        }
    }
}

extern "C" void kernel_launch(void* const* d_in, const int* in_sizes, int n_in,
                              void* d_out, int out_size, void* d_ws, size_t ws_size,
                              hipStream_t stream)
{
    const float* x  = (const float*)d_in[0];
    const float* h0 = (const float*)d_in[1];
    const float* Wz = (const float*)d_in[2];
    const float* bz = (const float*)d_in[3];
    const float* Wh = (const float*)d_in[4];
    const float* bh = (const float*)d_in[5];
    float* out = (float*)d_out;

    // Workspace: wzb/whb 131K each | agg 512K  => ~0.8 MB.
    unsigned char* ws = (unsigned char*)d_ws;
    unsigned short* wzb = (unsigned short*)ws;   ws += (size_t)kH * kD * 2;
    unsigned short* whb = (unsigned short*)ws;   ws += (size_t)kH * kD * 2;
    unsigned long long* agg = (unsigned long long*)ws;

    constexpr int PREP_ITEMS = 2 * (kH * kD / 4)
                             + kNChain * kNT * TH * 8 / 16;   // 65,536
    prep<<<PREP_ITEMS / 256, 256, 0, stream>>>(
        Wz, Wh, wzb, whb, (float4*)agg);
    gemm_scan_fused<<<kNChain * kNT, 256, 0, stream>>>(
        x, wzb, whb, bz, bh, h0, agg, out);
}